// Round 1
// baseline (6679.514 us; speedup 1.0000x reference)
//
#include <hip/hip_runtime.h>

#define BB 32
#define LL 1024
#define DDIM 768
#define TQ 8
#define NT 256
#define DC (DDIM / 4)        // 192 float4 per row
#define QSTRIDE (DDIM + 4)   // padded floats per sQ row (break 768%32==0 bank alias)
#define SSTRIDE (LL + 4)     // padded floats per sS row

// One block = (batch b, tile of TQ query rows, pass).
// pass 0: out1 = Attention(Q=X2, K=V=X1)  -> d_out[0 ..)
// pass 1: out2 = Attention(Q=X1, K=V=X2)  -> d_out[B*L*D ..)
__global__ __launch_bounds__(NT) void attn_fused(
    const float* __restrict__ X1, const float* __restrict__ X2,
    float* __restrict__ out)
{
    const int pass = blockIdx.z;
    const int b    = blockIdx.y;
    const int r0   = blockIdx.x * TQ;

    const float* __restrict__ Qg = (pass ? X1 : X2) + ((size_t)b * LL + r0) * DDIM;
    const float* __restrict__ Kg = (pass ? X2 : X1) + (size_t)b * LL * DDIM;
    float* __restrict__ Og = out + (size_t)pass * BB * LL * DDIM
                                 + ((size_t)b * LL + r0) * DDIM;

    __shared__ float sQ[TQ * QSTRIDE];   // ~24.1 KB
    __shared__ float sS[TQ * SSTRIDE];   // ~32.1 KB

    const int t = threadIdx.x;

    // ---- load Q tile into LDS (respect row padding) ----
    for (int i = t; i < TQ * DC; i += NT) {
        const int row = i / DC, c = i % DC;
        ((float4*)(sQ + row * QSTRIDE))[c] = ((const float4*)Qg)[i];
    }
    __syncthreads();

    // ---- S = Q K^T : thread handles q = t&7, columns k = (t>>3) + 32*w ----
    {
        const int q  = t & (TQ - 1);
        const int kg = t >> 3;                    // 0..31
        float acc[32];
        #pragma unroll
        for (int w = 0; w < 32; ++w) acc[w] = 0.f;
        const float4* __restrict__ Qrow = (const float4*)(sQ + q * QSTRIDE);
        const float4* __restrict__ K4   = (const float4*)Kg;
        for (int c = 0; c < DC; ++c) {
            const float4 qv = Qrow[c];
            #pragma unroll
            for (int w = 0; w < 32; ++w) {
                const float4 kv = K4[(kg + 32 * w) * DC + c];
                acc[w] = fmaf(qv.x, kv.x, acc[w]);
                acc[w] = fmaf(qv.y, kv.y, acc[w]);
                acc[w] = fmaf(qv.z, kv.z, acc[w]);
                acc[w] = fmaf(qv.w, kv.w, acc[w]);
            }
        }
        #pragma unroll
        for (int w = 0; w < 32; ++w) sS[q * SSTRIDE + kg + 32 * w] = acc[w];
    }
    __syncthreads();

    // ---- exact softmax over each of the TQ rows (32 lanes per row) ----
    {
        const int q = t >> 5;                     // 0..7
        const int l = t & 31;
        float* __restrict__ row = sS + q * SSTRIDE;

        float mx = -3.0e38f;
        for (int k = l; k < LL; k += 32) mx = fmaxf(mx, row[k]);
        #pragma unroll
        for (int off = 16; off > 0; off >>= 1) mx = fmaxf(mx, __shfl_xor(mx, off));

        float se = 0.f;
        for (int k = l; k < LL; k += 32) {
            const float e = __expf(row[k] - mx);
            row[k] = e;
            se += e;
        }
        #pragma unroll
        for (int off = 16; off > 0; off >>= 1) se += __shfl_xor(se, off);

        const float inv = 1.0f / se;
        for (int k = l; k < LL; k += 32) row[k] *= inv;
    }
    __syncthreads();

    // ---- O = P V : thread handles q = t&7, d-chunks c = (t>>3) + 32*r ----
    {
        const int q  = t & (TQ - 1);
        const int cg = t >> 3;                    // 0..31
        float4 acc[6];
        #pragma unroll
        for (int r = 0; r < 6; ++r) acc[r] = make_float4(0.f, 0.f, 0.f, 0.f);

        const float* __restrict__ P  = sS + q * SSTRIDE;
        const float4* __restrict__ V4 = (const float4*)Kg;
        for (int k = 0; k < LL; ++k) {
            const float p = P[k];
            if (p > 1e-8f) {                      // softmax is peaked; skip dead mass
                const float4* __restrict__ Vrow = V4 + (size_t)k * DC;
                #pragma unroll
                for (int r = 0; r < 6; ++r) {
                    const float4 v = Vrow[cg + 32 * r];
                    acc[r].x = fmaf(p, v.x, acc[r].x);
                    acc[r].y = fmaf(p, v.y, acc[r].y);
                    acc[r].z = fmaf(p, v.z, acc[r].z);
                    acc[r].w = fmaf(p, v.w, acc[r].w);
                }
            }
        }
        float4* __restrict__ O4 = (float4*)(Og + q * DDIM);
        #pragma unroll
        for (int r = 0; r < 6; ++r) O4[cg + 32 * r] = acc[r];
    }
}

extern "C" void kernel_launch(void* const* d_in, const int* in_sizes, int n_in,
                              void* d_out, int out_size, void* d_ws, size_t ws_size,
                              hipStream_t stream) {
    const float* X1 = (const float*)d_in[0];
    const float* X2 = (const float*)d_in[1];
    float* out = (float*)d_out;
    dim3 grid(LL / TQ, BB, 2);
    attn_fused<<<grid, dim3(NT), 0, stream>>>(X1, X2, out);
}

// Round 2
// 1489.683 us; speedup vs baseline: 4.4839x; 4.4839x over previous
//
#include <hip/hip_runtime.h>

typedef _Float16 half8 __attribute__((ext_vector_type(8)));
typedef _Float16 half4v __attribute__((ext_vector_type(4)));
typedef float floatx4 __attribute__((ext_vector_type(4)));

#define B_ 32
#define L_ 1024
#define D_ 768

// ---------------------------------------------------------------------------
// Kernel 0: convert fp32 -> fp16 hi/lo (row-major) + hi transposed [b][d][l].
// grid (L/64, D/64, B*2), block 256. One 64x64 tile per block.
// ---------------------------------------------------------------------------
__global__ __launch_bounds__(256) void convert_kernel(
    const float* __restrict__ X1, const float* __restrict__ X2,
    _Float16* __restrict__ X1h, _Float16* __restrict__ X1l, _Float16* __restrict__ X1hT,
    _Float16* __restrict__ X2h, _Float16* __restrict__ X2l, _Float16* __restrict__ X2hT)
{
    const int z = blockIdx.z;
    const int inp = z >> 5, b = z & 31;
    const float* __restrict__ X = inp ? X2 : X1;
    _Float16* __restrict__ Yh  = inp ? X2h  : X1h;
    _Float16* __restrict__ Yl  = inp ? X2l  : X1l;
    _Float16* __restrict__ YhT = inp ? X2hT : X1hT;

    const int l0 = blockIdx.x * 64, d0 = blockIdx.y * 64;
    const int t = threadIdx.x;

    __shared__ _Float16 sT[64 * 76];   // [l][d], stride 76

    #pragma unroll
    for (int it = 0; it < 4; ++it) {
        const int row = (t >> 4) + it * 16;   // 0..63 (l within tile)
        const int c4  = t & 15;               // 0..15 (d/4 within tile)
        const float4 x = *(const float4*)(X + ((size_t)b * L_ + l0 + row) * D_ + d0 + c4 * 4);
        _Float16 h0 = (_Float16)x.x, h1 = (_Float16)x.y, h2 = (_Float16)x.z, h3 = (_Float16)x.w;
        half4v hh = {h0, h1, h2, h3};
        half4v ll = {(_Float16)(x.x - (float)h0), (_Float16)(x.y - (float)h1),
                     (_Float16)(x.z - (float)h2), (_Float16)(x.w - (float)h3)};
        const size_t gidx = ((size_t)b * L_ + l0 + row) * D_ + d0 + c4 * 4;
        *(half4v*)(Yh + gidx) = hh;
        *(half4v*)(Yl + gidx) = ll;
        *(half4v*)(&sT[row * 76 + c4 * 4]) = hh;
    }
    __syncthreads();
    #pragma unroll
    for (int it = 0; it < 2; ++it) {
        const int dr = (t >> 3) + it * 32;    // 0..63 (d within tile)
        const int l8 = t & 7;                 // 0..7  (l/8 within tile)
        half8 v;
        #pragma unroll
        for (int j = 0; j < 8; ++j) v[j] = sT[(l8 * 8 + j) * 76 + dr];
        *(half8*)(YhT + ((size_t)b * D_ + d0 + dr) * L_ + l0 + l8 * 8) = v;
    }
}

// ---------------------------------------------------------------------------
// Kernel 1: fused flash-style dual attention with fp16 MFMA (hi/lo split S).
// grid (L/32, B, 2), block 256 (4 waves). LDS ~57 KB -> 2 blocks/CU.
// wave roles: mi = w&1 (16-row m-tile), nh = w>>1 (key-half in S / d-half in PV)
// ---------------------------------------------------------------------------
#define MT 32
#define KT 64
#define DCH 128
#define NCH (D_ / DCH)   // 6
#define NNT (L_ / KT)    // 16
#define QS 136           // sQ/sK fp16 row stride (128 + 8 pad)
#define VS 72            // sVt/sP fp16 row stride (64 + 8 pad)
#define SS 76            // sS fp32 row stride (64 + 12 pad)

__global__ __launch_bounds__(256, 2) void attn_mfma(
    const _Float16* __restrict__ X1h, const _Float16* __restrict__ X1l,
    const _Float16* __restrict__ X1hT,
    const _Float16* __restrict__ X2h, const _Float16* __restrict__ X2l,
    const _Float16* __restrict__ X2hT,
    float* __restrict__ out)
{
    const int pass = blockIdx.z, b = blockIdx.y, q0 = blockIdx.x * MT;

    const _Float16* __restrict__ Qh = pass ? X1h : X2h;
    const _Float16* __restrict__ Ql = pass ? X1l : X2l;
    const _Float16* __restrict__ Kh = pass ? X2h : X1h;
    const _Float16* __restrict__ Kl = pass ? X2l : X1l;
    const _Float16* __restrict__ VT = pass ? X2hT : X1hT;

    const _Float16* __restrict__ Qhb = Qh + ((size_t)b * L_ + q0) * D_;
    const _Float16* __restrict__ Qlb = Ql + ((size_t)b * L_ + q0) * D_;
    const _Float16* __restrict__ Khb = Kh + (size_t)b * L_ * D_;
    const _Float16* __restrict__ Klb = Kl + (size_t)b * L_ * D_;
    const _Float16* __restrict__ VTb = VT + (size_t)b * D_ * L_;

    // LDS arena (overlaid phases) + persistent buffers
    __shared__ __align__(16) unsigned char smem[57216];
    _Float16* sQh = (_Float16*)smem;                  // [32][136] 8704 B
    _Float16* sQl = (_Float16*)(smem + 8704);
    _Float16* sKh = (_Float16*)(smem + 17408);        // [64][136] 17408 B
    _Float16* sKl = (_Float16*)(smem + 34816);
    float*    sS  = (float*)smem;                     // [32][76] fp32 (overlay)
    _Float16* sVt = (_Float16*)smem;                  // [128][72] fp16 (overlay)
    _Float16* sP  = (_Float16*)(smem + 52224);        // [32][72] fp16, 4608 B
    float*    sM  = (float*)(smem + 56832);           // [32]
    float*    sL  = (float*)(smem + 56960);           // [32]
    float*    sA  = (float*)(smem + 57088);           // [32]

    const int t = threadIdx.x;
    const int w = t >> 6, lane = t & 63;
    const int mi = w & 1, nh = w >> 1;
    const int lr = lane & 15, kg = lane >> 4;

    floatx4 O[24];
    #pragma unroll
    for (int i = 0; i < 24; ++i) O[i] = 0;

    if (t < 32) { sM[t] = -3.0e38f; sL[t] = 0.f; }

    for (int nt = 0; nt < NNT; ++nt) {
        floatx4 Cs0 = 0, Cs1 = 0;
        const _Float16* __restrict__ Kth = Khb + (size_t)(nt * KT) * D_;
        const _Float16* __restrict__ Ktl = Klb + (size_t)(nt * KT) * D_;

        // ---- S phase: accumulate S(32x64) over 6 d-chunks of 128 ----
        for (int dc = 0; dc < NCH; ++dc) {
            __syncthreads();
            #pragma unroll
            for (int i = 0; i < 2; ++i) {
                const int v = t + 256 * i;
                const int row = v >> 4, c8 = v & 15;
                *(half8*)(sQh + row * QS + c8 * 8) =
                    *(const half8*)(Qhb + row * D_ + dc * DCH + c8 * 8);
                *(half8*)(sQl + row * QS + c8 * 8) =
                    *(const half8*)(Qlb + row * D_ + dc * DCH + c8 * 8);
            }
            #pragma unroll
            for (int i = 0; i < 4; ++i) {
                const int v = t + 256 * i;
                const int row = v >> 4, c8 = v & 15;
                *(half8*)(sKh + row * QS + c8 * 8) =
                    *(const half8*)(Kth + row * D_ + dc * DCH + c8 * 8);
                *(half8*)(sKl + row * QS + c8 * 8) =
                    *(const half8*)(Ktl + row * D_ + dc * DCH + c8 * 8);
            }
            __syncthreads();
            #pragma unroll
            for (int ks = 0; ks < 4; ++ks) {
                const int ko = ks * 32 + kg * 8;
                half8 aH  = *(const half8*)(sQh + (mi * 16 + lr) * QS + ko);
                half8 aL  = *(const half8*)(sQl + (mi * 16 + lr) * QS + ko);
                half8 b0H = *(const half8*)(sKh + (nh * 32 + lr) * QS + ko);
                half8 b0L = *(const half8*)(sKl + (nh * 32 + lr) * QS + ko);
                half8 b1H = *(const half8*)(sKh + (nh * 32 + 16 + lr) * QS + ko);
                half8 b1L = *(const half8*)(sKl + (nh * 32 + 16 + lr) * QS + ko);
                Cs0 = __builtin_amdgcn_mfma_f32_16x16x32_f16(aH, b0H, Cs0, 0, 0, 0);
                Cs1 = __builtin_amdgcn_mfma_f32_16x16x32_f16(aH, b1H, Cs1, 0, 0, 0);
                Cs0 = __builtin_amdgcn_mfma_f32_16x16x32_f16(aH, b0L, Cs0, 0, 0, 0);
                Cs1 = __builtin_amdgcn_mfma_f32_16x16x32_f16(aH, b1L, Cs1, 0, 0, 0);
                Cs0 = __builtin_amdgcn_mfma_f32_16x16x32_f16(aL, b0H, Cs0, 0, 0, 0);
                Cs1 = __builtin_amdgcn_mfma_f32_16x16x32_f16(aL, b1H, Cs1, 0, 0, 0);
            }
        }
        __syncthreads();
        // ---- write S tile (C-layout: col=lane&15, row=kg*4+reg) ----
        #pragma unroll
        for (int r = 0; r < 4; ++r) {
            sS[(mi * 16 + kg * 4 + r) * SS + nh * 32 + lr]      = Cs0[r];
            sS[(mi * 16 + kg * 4 + r) * SS + nh * 32 + 16 + lr] = Cs1[r];
        }
        __syncthreads();
        // ---- online softmax: 8 threads per q-row ----
        {
            const int row = t >> 3, l8 = t & 7;
            const floatx4 s0 = *(const floatx4*)(sS + row * SS + l8 * 8);
            const floatx4 s1 = *(const floatx4*)(sS + row * SS + l8 * 8 + 4);
            float mt = fmaxf(fmaxf(fmaxf(s0[0], s0[1]), fmaxf(s0[2], s0[3])),
                             fmaxf(fmaxf(s1[0], s1[1]), fmaxf(s1[2], s1[3])));
            mt = fmaxf(mt, __shfl_xor(mt, 1));
            mt = fmaxf(mt, __shfl_xor(mt, 2));
            mt = fmaxf(mt, __shfl_xor(mt, 4));
            const float mo = sM[row];
            const float mn = fmaxf(mo, mt);
            float e[8];
            e[0] = __expf(s0[0] - mn); e[1] = __expf(s0[1] - mn);
            e[2] = __expf(s0[2] - mn); e[3] = __expf(s0[3] - mn);
            e[4] = __expf(s1[0] - mn); e[5] = __expf(s1[1] - mn);
            e[6] = __expf(s1[2] - mn); e[7] = __expf(s1[3] - mn);
            half8 hp;
            float sum = 0.f;
            #pragma unroll
            for (int j = 0; j < 8; ++j) { hp[j] = (_Float16)e[j]; sum += (float)hp[j]; }
            sum += __shfl_xor(sum, 1);
            sum += __shfl_xor(sum, 2);
            sum += __shfl_xor(sum, 4);
            *(half8*)(sP + row * VS + l8 * 8) = hp;
            if (l8 == 0) {
                const float al = __expf(mo - mn);
                sM[row] = mn;
                sL[row] = sL[row] * al + sum;
                sA[row] = al;
            }
        }
        __syncthreads();
        // ---- rescale O by alpha (rows = mi*16 + kg*4 + r) ----
        {
            const floatx4 al4 = *(const floatx4*)(sA + mi * 16 + kg * 4);
            #pragma unroll
            for (int i = 0; i < 24; ++i) O[i] *= al4;
        }
        // ---- P A-frags (keys 0..31 and 32..63) ----
        const half8 aP0 = *(const half8*)(sP + (mi * 16 + lr) * VS + kg * 8);
        const half8 aP1 = *(const half8*)(sP + (mi * 16 + lr) * VS + 32 + kg * 8);
        // ---- PV: 6 d-chunks of 128, wave owns d-half nh (4 d-tiles/chunk) ----
        for (int dc = 0; dc < NCH; ++dc) {
            __syncthreads();
            #pragma unroll
            for (int i = 0; i < 4; ++i) {
                const int v = t + 256 * i;
                const int row = v >> 3, k8 = v & 7;   // row = d within chunk
                *(half8*)(sVt + row * VS + k8 * 8) =
                    *(const half8*)(VTb + (size_t)(dc * DCH + row) * L_ + nt * KT + k8 * 8);
            }
            __syncthreads();
            #pragma unroll
            for (int j = 0; j < 4; ++j) {
                const int dl = nh * 64 + j * 16;
                half8 b0 = *(const half8*)(sVt + (dl + lr) * VS + kg * 8);
                half8 b1 = *(const half8*)(sVt + (dl + lr) * VS + 32 + kg * 8);
                O[dc * 4 + j] = __builtin_amdgcn_mfma_f32_16x16x32_f16(aP0, b0, O[dc * 4 + j], 0, 0, 0);
                O[dc * 4 + j] = __builtin_amdgcn_mfma_f32_16x16x32_f16(aP1, b1, O[dc * 4 + j], 0, 0, 0);
            }
        }
    }

    __syncthreads();
    // ---- epilogue: normalize by l and store ----
    {
        const floatx4 lv = *(const floatx4*)(sL + mi * 16 + kg * 4);
        floatx4 linv;
        #pragma unroll
        for (int r = 0; r < 4; ++r) linv[r] = 1.0f / lv[r];
        float* __restrict__ outB = out + (size_t)pass * B_ * L_ * D_
                                 + ((size_t)b * L_ + q0 + mi * 16 + kg * 4) * D_;
        #pragma unroll
        for (int dc = 0; dc < NCH; ++dc) {
            #pragma unroll
            for (int j = 0; j < 4; ++j) {
                const int d0 = dc * DCH + nh * 64 + j * 16 + lr;
                const floatx4 o = O[dc * 4 + j] * linv;
                #pragma unroll
                for (int r = 0; r < 4; ++r) outB[(size_t)r * D_ + d0] = o[r];
            }
        }
    }
}

// ---------------------------------------------------------------------------
// Fallback (round-1 fp32 kernel) if ws is too small for the fp16 staging.
// ---------------------------------------------------------------------------
#define TQ 8
#define NTF 256
#define DC (D_ / 4)
#define QSTRIDE (D_ + 4)
#define SSTRIDE (L_ + 4)

__global__ __launch_bounds__(NTF) void attn_fused_fallback(
    const float* __restrict__ X1, const float* __restrict__ X2,
    float* __restrict__ out)
{
    const int pass = blockIdx.z;
    const int b    = blockIdx.y;
    const int r0   = blockIdx.x * TQ;

    const float* __restrict__ Qg = (pass ? X1 : X2) + ((size_t)b * L_ + r0) * D_;
    const float* __restrict__ Kg = (pass ? X2 : X1) + (size_t)b * L_ * D_;
    float* __restrict__ Og = out + (size_t)pass * B_ * L_ * D_
                                 + ((size_t)b * L_ + r0) * D_;

    __shared__ float sQ[TQ * QSTRIDE];
    __shared__ float sS2[TQ * SSTRIDE];

    const int t = threadIdx.x;

    for (int i = t; i < TQ * DC; i += NTF) {
        const int row = i / DC, c = i % DC;
        ((float4*)(sQ + row * QSTRIDE))[c] = ((const float4*)Qg)[i];
    }
    __syncthreads();

    {
        const int q  = t & (TQ - 1);
        const int kgI = t >> 3;
        float acc[32];
        #pragma unroll
        for (int w2 = 0; w2 < 32; ++w2) acc[w2] = 0.f;
        const float4* __restrict__ Qrow = (const float4*)(sQ + q * QSTRIDE);
        const float4* __restrict__ K4   = (const float4*)Kg;
        for (int c = 0; c < DC; ++c) {
            const float4 qv = Qrow[c];
            #pragma unroll
            for (int w2 = 0; w2 < 32; ++w2) {
                const float4 kv = K4[(kgI + 32 * w2) * DC + c];
                acc[w2] = fmaf(qv.x, kv.x, acc[w2]);
                acc[w2] = fmaf(qv.y, kv.y, acc[w2]);
                acc[w2] = fmaf(qv.z, kv.z, acc[w2]);
                acc[w2] = fmaf(qv.w, kv.w, acc[w2]);
            }
        }
        #pragma unroll
        for (int w2 = 0; w2 < 32; ++w2) sS2[q * SSTRIDE + kgI + 32 * w2] = acc[w2];
    }
    __syncthreads();

    {
        const int q = t >> 5;
        const int l = t & 31;
        float* __restrict__ row = sS2 + q * SSTRIDE;
        float mx = -3.0e38f;
        for (int k = l; k < L_; k += 32) mx = fmaxf(mx, row[k]);
        #pragma unroll
        for (int off = 16; off > 0; off >>= 1) mx = fmaxf(mx, __shfl_xor(mx, off));
        float se = 0.f;
        for (int k = l; k < L_; k += 32) {
            const float e = __expf(row[k] - mx);
            row[k] = e;
            se += e;
        }
        #pragma unroll
        for (int off = 16; off > 0; off >>= 1) se += __shfl_xor(se, off);
        const float inv = 1.0f / se;
        for (int k = l; k < L_; k += 32) row[k] *= inv;
    }
    __syncthreads();

    {
        const int q  = t & (TQ - 1);
        const int cg = t >> 3;
        float4 acc[6];
        #pragma unroll
        for (int r = 0; r < 6; ++r) acc[r] = make_float4(0.f, 0.f, 0.f, 0.f);
        const float* __restrict__ P   = sS2 + q * SSTRIDE;
        const float4* __restrict__ V4 = (const float4*)Kg;
        for (int k = 0; k < L_; ++k) {
            const float p = P[k];
            if (p > 1e-8f) {
                const float4* __restrict__ Vrow = V4 + (size_t)k * DC;
                #pragma unroll
                for (int r = 0; r < 6; ++r) {
                    const float4 v = Vrow[cg + 32 * r];
                    acc[r].x = fmaf(p, v.x, acc[r].x);
                    acc[r].y = fmaf(p, v.y, acc[r].y);
                    acc[r].z = fmaf(p, v.z, acc[r].z);
                    acc[r].w = fmaf(p, v.w, acc[r].w);
                }
            }
        }
        float4* __restrict__ O4 = (float4*)(Og + q * D_);
        #pragma unroll
        for (int r = 0; r < 6; ++r) O4[cg + 32 * r] = acc[r];
    }
}

extern "C" void kernel_launch(void* const* d_in, const int* in_sizes, int n_in,
                              void* d_out, int out_size, void* d_ws, size_t ws_size,
                              hipStream_t stream) {
    const float* X1 = (const float*)d_in[0];
    const float* X2 = (const float*)d_in[1];
    float* out = (float*)d_out;

    const size_t arr  = (size_t)B_ * L_ * D_;       // 25,165,824 elems
    const size_t need = arr * 2 * 6;                // 6 fp16 arrays = 288 MB

    if (ws_size >= need) {
        _Float16* X1h  = (_Float16*)d_ws;
        _Float16* X1l  = X1h + arr;
        _Float16* X2h  = X1l + arr;
        _Float16* X2l  = X2h + arr;
        _Float16* X1hT = X2l + arr;
        _Float16* X2hT = X1hT + arr;
        convert_kernel<<<dim3(L_ / 64, D_ / 64, B_ * 2), dim3(256), 0, stream>>>(
            X1, X2, X1h, X1l, X1hT, X2h, X2l, X2hT);
        attn_mfma<<<dim3(L_ / MT, B_, 2), dim3(256), 0, stream>>>(
            X1h, X1l, X1hT, X2h, X2l, X2hT, out);
    } else {
        attn_fused_fallback<<<dim3(L_ / TQ, B_, 2), dim3(NTF), 0, stream>>>(X1, X2, out);
    }
}